// Round 12
// baseline (698.040 us; speedup 1.0000x reference)
//
#include <hip/hip_runtime.h>
#include <hip/hip_bf16.h>
#include <hip/hip_cooperative_groups.h>

namespace cg = cooperative_groups;

#define NNODES 100000
#define NEDGES 1600000
#define IN_CH 128
#define HID 64
#define NC 40
#define NPAD 100352   // NNODES padded to multiple of 256
#define NBUK 196      // ceil(100000 / 512) dst-buckets of 512 nodes
#define CAP 9216      // per-bucket tmp capacity (mean 8192, sigma ~90 -> 11 sigma)
#define BCH 2560      // bin chunk (fits the 38.9 KB LDS union)
#define GRID 1024     // 256 CUs x 4 blocks/CU (validated by cooperative launch)

typedef unsigned short ushort_t;
typedef unsigned int uint_t;
typedef __attribute__((ext_vector_type(8))) short short8;
typedef __attribute__((ext_vector_type(4))) float floatx4;
typedef __attribute__((ext_vector_type(2))) float f32x2;

__device__ __forceinline__ ushort_t f2bf(float f) {
    union { float ff; unsigned int i; } t;
    t.ff = f;
    unsigned int r = t.i + 0x7fff + ((t.i >> 16) & 1);  // RNE
    return (ushort_t)(r >> 16);
}
__device__ __forceinline__ void acc2(f32x2& a, uint_t p) {
    union { unsigned int i; float f; } lo, hi;
    lo.i = p << 16;
    hi.i = p & 0xffff0000u;
    f32x2 v = {lo.f, hi.f};
    a += v;
}

// ---- phase-overlaid LDS ----
struct SmBin {
    uint_t pk[BCH]; ushort_t bk[BCH];     // input order
    uint_t spk[BCH]; ushort_t sb[BCH];    // bucket-sorted
    int hist[NBUK]; int lscan[NBUK]; int base[NBUK]; int sc2[256];
};
struct SmSortScan { int sc[512]; int red[256]; };
struct SmSort { int cnt[512]; union { SmSortScan s; uint_t esl[CAP]; } u; };
struct SmG2 { float wsm[HID * NC]; float hsm[32][68]; };
union Sm { SmBin bin; SmSort sort; SmG2 g2; };
static_assert(sizeof(Sm) <= 39936, "LDS budget for 4 blocks/CU");

// ================= shared phase bodies (verified round-10 code) =================

__device__ __forceinline__ void side_work(const float* __restrict__ W1,
                                          ushort_t* __restrict__ Wp,
                                          ushort_t* __restrict__ hb, int n, int t) {
    for (int i = t; i < IN_CH * HID; i += 256) {
        int j = i & 7;
        int m = (i >> 3) & 15;
        int ct = (i >> 7) & 3;
        int quad = (i >> 9) & 3;
        int kc = i >> 11;
        int k = kc * 32 + quad * 8 + j;
        int c = ct * 16 + m;
        Wp[i] = f2bf(W1[k * HID + c]);
    }
    uint_t* hbz = (uint_t*)(hb + (size_t)n * HID);
    if (t < 32) hbz[t] = 0;      // 64 bf16 zeros (sentinel row n)
}

__device__ __forceinline__ void bin_chunk(SmBin& sm, int chunk,
    const int* __restrict__ srcs, const int* __restrict__ dsts,
    int* __restrict__ gcur, uint_t* __restrict__ tmp, int e, int t)
{
    int begin = chunk * BCH;
    int ec = e - begin; if (ec > BCH) ec = BCH;
    for (int i = t; i < NBUK; i += 256) sm.hist[i] = 0;
    __syncthreads();
    for (int j = t; j < ec; j += 256) {
        int d = dsts[begin + j];
        int s = srcs[begin + j];
        int b = d >> 9;
        sm.pk[j] = (uint_t)s | ((uint_t)(d & 511) << 17);
        sm.bk[j] = (ushort_t)b;
        atomicAdd(&sm.hist[b], 1);
    }
    __syncthreads();
    int c = (t < NBUK) ? sm.hist[t] : 0;
    sm.sc2[t] = c;
    __syncthreads();
    for (int off = 1; off < 256; off <<= 1) {
        int v = (t >= off) ? sm.sc2[t - off] : 0;
        __syncthreads();
        sm.sc2[t] += v;
        __syncthreads();
    }
    if (t < NBUK) {
        sm.lscan[t] = sm.sc2[t] - c;
        sm.base[t] = t * CAP + atomicAdd(&gcur[t], c);
        sm.hist[t] = 0;          // reuse as rank cursor
    }
    __syncthreads();
    for (int j = t; j < ec; j += 256) {
        int b = sm.bk[j];
        int r = atomicAdd(&sm.hist[b], 1);
        int slot = sm.lscan[b] + r;
        sm.spk[slot] = sm.pk[j];
        sm.sb[slot] = (ushort_t)b;
    }
    __syncthreads();
    for (int j = t; j < ec; j += 256) {
        int b = sm.sb[j];
        int pos = sm.base[b] + (j - sm.lscan[b]);
        if (pos < (b + 1) * CAP) tmp[pos] = sm.spk[j];
    }
    __syncthreads();             // LDS reused next chunk
}

__device__ __forceinline__ void sort_bucket(SmSort& sm, int b,
    const uint_t* __restrict__ tmp, const int* __restrict__ gcur,
    int* __restrict__ row_start, float* __restrict__ dinv,
    uint_t* __restrict__ es, int n, int e, int t)
{
    int d0 = b << 9;
    int total = gcur[b];
    if (total > CAP) total = CAP;
    int part = 0;
    for (int i = t; i < b; i += 256) part += gcur[i];
    sm.u.s.red[t] = part;
    sm.cnt[t] = 0; sm.cnt[t + 256] = 0;
    __syncthreads();
    for (int off = 128; off > 0; off >>= 1) {
        if (t < off) sm.u.s.red[t] += sm.u.s.red[t + off];
        __syncthreads();
    }
    int gb = sm.u.s.red[0];
    const uint_t* seg = tmp + b * CAP;
    for (int j = t; j < total; j += 256)
        atomicAdd(&sm.cnt[seg[j] >> 17], 1);
    __syncthreads();
    sm.u.s.sc[t] = sm.cnt[t]; sm.u.s.sc[t + 256] = sm.cnt[t + 256];
    __syncthreads();
    for (int off = 1; off < 512; off <<= 1) {
        int v0 = (t >= off) ? sm.u.s.sc[t - off] : 0;
        int i1 = t + 256;
        int v1 = (i1 >= off) ? sm.u.s.sc[i1 - off] : 0;
        __syncthreads();
        sm.u.s.sc[t] += v0; sm.u.s.sc[i1] += v1;
        __syncthreads();
    }
#pragma unroll
    for (int q = 0; q < 2; ++q) {
        int i = t + q * 256;
        int node = d0 + i;
        int start = gb + sm.u.s.sc[i] - sm.cnt[i];
        if (node < n) {
            row_start[node] = start;
            dinv[node] = rsqrtf((float)sm.cnt[i] + 1.0f);
        }
        sm.cnt[i] = start - gb;   // local scatter cursor (segment-relative)
    }
    __syncthreads();              // sc/red dead -> esl may overwrite
    for (int j = t; j < total; j += 256) {
        uint_t p = seg[j];
        int ld = (int)(p >> 17);
        int pos = atomicAdd(&sm.cnt[ld], 1);
        sm.u.esl[pos] = p & 0x1FFFFu;
    }
    __syncthreads();
    for (int j = t; j < total; j += 256) es[gb + j] = sm.u.esl[j];
    if (b == NBUK - 1 && t == 0) row_start[n] = e;
    __syncthreads();
}

__device__ __forceinline__ void gemm1_tile(int g,
    const float* __restrict__ x, const ushort_t* __restrict__ Wp,
    const float* __restrict__ dinv, ushort_t* __restrict__ hw1, int n, int t)
{
    int wave = t >> 6;
    int lane = t & 63;
    int m = lane & 15;
    int quad = lane >> 4;
    int row = g * 64 + wave * 16 + m;
    int rowc = row < n ? row : (n - 1);
    const float* xr = x + (size_t)rowc * IN_CH + quad * 8;
    floatx4 acc[4];
#pragma unroll
    for (int ct = 0; ct < 4; ++ct) acc[ct] = (floatx4){0.f, 0.f, 0.f, 0.f};
#pragma unroll
    for (int kc = 0; kc < 4; ++kc) {
        float4 xa = *(const float4*)(xr + kc * 32);
        float4 xb = *(const float4*)(xr + kc * 32 + 4);
        short8 a;
        a[0] = (short)f2bf(xa.x); a[1] = (short)f2bf(xa.y);
        a[2] = (short)f2bf(xa.z); a[3] = (short)f2bf(xa.w);
        a[4] = (short)f2bf(xb.x); a[5] = (short)f2bf(xb.y);
        a[6] = (short)f2bf(xb.z); a[7] = (short)f2bf(xb.w);
#pragma unroll
        for (int ct = 0; ct < 4; ++ct) {
            short8 bfr = *(const short8*)(Wp + ((((kc * 4 + quad) * 4 + ct) * 16 + m) << 3));
            acc[ct] = __builtin_amdgcn_mfma_f32_16x16x32_bf16(a, bfr, acc[ct], 0, 0, 0);
        }
    }
    int r0 = g * 64 + wave * 16 + quad * 4;
#pragma unroll
    for (int r = 0; r < 4; ++r) {
        int rr = r0 + r;
        if (rr < n) {
            float di = dinv[rr];
            ushort_t* o = hw1 + (size_t)rr * HID + m;
#pragma unroll
            for (int ct = 0; ct < 4; ++ct) o[ct * 16] = f2bf(acc[ct][r] * di);
        } else if (rr == n) {
            ushort_t* o = hw1 + (size_t)n * HID + m;
#pragma unroll
            for (int ct = 0; ct < 4; ++ct) o[ct * 16] = 0;
        }
    }
}

__device__ __forceinline__ void agg1_tile(int g,
    const int* __restrict__ row_start, const uint_t* __restrict__ es,
    const float* __restrict__ dinv, const uint_t* __restrict__ hw1u,
    const float* __restrict__ b1, ushort_t* __restrict__ hb, int n, int t)
{
    int lane = t & 63;
    int obase = lane & 56;
    int ol = lane & 7;
    int node = g * 32 + (t >> 3);
    bool valid = node < n;
    int rs = valid ? row_start[node] : 0;
    int re = valid ? row_start[node + 1] : 0;
    float di = valid ? dinv[node] : 0.f;
    int selfrow = valid ? node : n;
    f32x2 c0, c1, c2, c3;
    {
        uint4 sp = *(const uint4*)(hw1u + (size_t)selfrow * 32 + ol * 4);
        c0 = (f32x2){0.f, 0.f}; c1 = c0; c2 = c0; c3 = c0;
        acc2(c0, sp.x); acc2(c1, sp.y); acc2(c2, sp.z); acc2(c3, sp.w);
    }
    int el = n;
    if (rs < re) {
        int idx = rs + ol;
        el = (idx < re) ? (int)es[idx] : n;   // pad -> zero sentinel
    }
    for (int base = rs; base < re; base += 8) {
        int el_cur = el;
        int nb = base + 8;
        if (nb < re) {                         // prefetch next window's indices
            int idx = nb + ol;
            el = (idx < re) ? (int)es[idx] : n;
        }
        uint4 p[8];
#pragma unroll
        for (int b = 0; b < 8; ++b) {
            int s = __shfl(el_cur, obase + b);
            p[b] = *(const uint4*)(hw1u + (size_t)s * 32 + ol * 4);
        }
#pragma unroll
        for (int b = 0; b < 8; ++b) {
            acc2(c0, p[b].x); acc2(c1, p[b].y);
            acc2(c2, p[b].z); acc2(c3, p[b].w);
        }
    }
    if (valid) {
        float4 bb0 = ((const float4*)b1)[ol * 2];
        float4 bb1 = ((const float4*)b1)[ol * 2 + 1];
        float h0 = fmaxf(c0.x * di + bb0.x, 0.f);
        float h1 = fmaxf(c0.y * di + bb0.y, 0.f);
        float h2 = fmaxf(c1.x * di + bb0.z, 0.f);
        float h3 = fmaxf(c1.y * di + bb0.w, 0.f);
        float h4 = fmaxf(c2.x * di + bb1.x, 0.f);
        float h5 = fmaxf(c2.y * di + bb1.y, 0.f);
        float h6 = fmaxf(c3.x * di + bb1.z, 0.f);
        float h7 = fmaxf(c3.y * di + bb1.w, 0.f);
        uint4 st;
        st.x = (uint_t)f2bf(h0 * di) | ((uint_t)f2bf(h1 * di) << 16);
        st.y = (uint_t)f2bf(h2 * di) | ((uint_t)f2bf(h3 * di) << 16);
        st.z = (uint_t)f2bf(h4 * di) | ((uint_t)f2bf(h5 * di) << 16);
        st.w = (uint_t)f2bf(h6 * di) | ((uint_t)f2bf(h7 * di) << 16);
        *(uint4*)(hb + (size_t)node * HID + ol * 8) = st;
    }
}

__device__ __forceinline__ void agg2_tile(SmG2& sm, int g,
    const int* __restrict__ row_start, const uint_t* __restrict__ es,
    const float* __restrict__ dinv, const uint_t* __restrict__ hbu,
    const float* __restrict__ b2, float* __restrict__ out, int n, int t)
{
    int lane = t & 63;
    int obase = lane & 56;
    int ol = lane & 7;
    int slot = t >> 3;
    int node = g * 32 + slot;
    bool valid = node < n;
    int rs = valid ? row_start[node] : 0;
    int re = valid ? row_start[node + 1] : 0;
    float di = valid ? dinv[node] : 0.f;
    int selfrow = valid ? node : n;
    f32x2 c0, c1, c2, c3;
    {
        uint4 sp = *(const uint4*)(hbu + (size_t)selfrow * 32 + ol * 4);
        c0 = (f32x2){0.f, 0.f}; c1 = c0; c2 = c0; c3 = c0;
        acc2(c0, sp.x); acc2(c1, sp.y); acc2(c2, sp.z); acc2(c3, sp.w);
    }
    int el = n;
    if (rs < re) {
        int idx = rs + ol;
        el = (idx < re) ? (int)es[idx] : n;
    }
    for (int base = rs; base < re; base += 8) {
        int el_cur = el;
        int nb = base + 8;
        if (nb < re) {
            int idx = nb + ol;
            el = (idx < re) ? (int)es[idx] : n;
        }
        uint4 p[8];
#pragma unroll
        for (int b = 0; b < 8; ++b) {
            int s = __shfl(el_cur, obase + b);
            p[b] = *(const uint4*)(hbu + (size_t)s * 32 + ol * 4);
        }
#pragma unroll
        for (int b = 0; b < 8; ++b) {
            acc2(c0, p[b].x); acc2(c1, p[b].y);
            acc2(c2, p[b].z); acc2(c3, p[b].w);
        }
    }
    {
        float4 g0, g1;
        g0.x = c0.x * di; g0.y = c0.y * di; g0.z = c1.x * di; g0.w = c1.y * di;
        g1.x = c2.x * di; g1.y = c2.y * di; g1.z = c3.x * di; g1.w = c3.y * di;
        *(float4*)&sm.hsm[slot][ol * 8] = g0;
        *(float4*)&sm.hsm[slot][ol * 8 + 4] = g1;
    }
    // fused GEMM2: same-wave LDS dot (no barrier needed)
    int w8 = (t >> 6) * 8;
    int qm = lane >> 4;
    int lq = lane & 15;
    int lw = (lq < 10) ? lq : 0;
    const float4* w4 = (const float4*)sm.wsm;
#pragma unroll
    for (int pass = 0; pass < 2; ++pass) {
        int slot2 = w8 + pass * 4 + qm;
        int node2 = g * 32 + slot2;
        float4 acc = ((const float4*)b2)[lw];
#pragma unroll 4
        for (int k4 = 0; k4 < 16; ++k4) {
            float4 hk = *(const float4*)&sm.hsm[slot2][k4 * 4];
            float4 w0 = w4[(k4 * 4 + 0) * 10 + lw];
            float4 w1 = w4[(k4 * 4 + 1) * 10 + lw];
            float4 w2 = w4[(k4 * 4 + 2) * 10 + lw];
            float4 w3 = w4[(k4 * 4 + 3) * 10 + lw];
            acc.x += hk.x * w0.x + hk.y * w1.x + hk.z * w2.x + hk.w * w3.x;
            acc.y += hk.x * w0.y + hk.y * w1.y + hk.z * w2.y + hk.w * w3.y;
            acc.z += hk.x * w0.z + hk.y * w1.z + hk.z * w2.z + hk.w * w3.z;
            acc.w += hk.x * w0.w + hk.y * w1.w + hk.z * w2.w + hk.w * w3.w;
        }
        if (node2 < n && lq < 10)
            *(float4*)(out + (size_t)node2 * NC + lq * 4) = acc;
    }
}

// ================= fused cooperative pipeline =================
extern "C" __global__ void __launch_bounds__(256, 4) k_all(
    const int* __restrict__ srcs, const int* __restrict__ dsts,
    int* __restrict__ gcur, uint_t* __restrict__ tmp,
    const float* __restrict__ W1, ushort_t* __restrict__ Wp,
    ushort_t* __restrict__ hb,
    int* __restrict__ row_start, float* __restrict__ dinv,
    uint_t* __restrict__ es,
    const float* __restrict__ x, ushort_t* __restrict__ hw1,
    const float* __restrict__ b1,
    const float* __restrict__ W2, const float* __restrict__ b2,
    float* __restrict__ out, int n, int e)
{
    __shared__ Sm sm;
    cg::grid_group grid = cg::this_grid();
    int t = threadIdx.x;
    int nchunk = (e + BCH - 1) / BCH;

    // phase 1: bin (+ side work on one idle block)
    if ((int)blockIdx.x == nchunk) side_work(W1, Wp, hb, n, t);
    for (int chunk = blockIdx.x; chunk < nchunk; chunk += GRID)
        bin_chunk(sm.bin, chunk, srcs, dsts, gcur, tmp, e, t);
    grid.sync();

    // phase 2: sort
    for (int b = blockIdx.x; b < NBUK; b += GRID)
        sort_bucket(sm.sort, b, tmp, gcur, row_start, dinv, es, n, e, t);
    grid.sync();

    // phase 3: GEMM1
    {
        int ng = (n + 63) >> 6;
        for (int g = blockIdx.x; g < ng; g += GRID)
            gemm1_tile(g, x, Wp, dinv, hw1, n, t);
    }
    grid.sync();

    // phase 4: agg1
    {
        const uint_t* hw1u = (const uint_t*)hw1;
        int nga = (n + 31) >> 5;
        for (int g = blockIdx.x; g < nga; g += GRID)
            agg1_tile(g, row_start, es, dinv, hw1u, b1, hb, n, t);
    }
    grid.sync();

    // phase 5: agg2 + fused GEMM2
    {
        const uint_t* hbu = (const uint_t*)hb;
        for (int i = t; i < HID * NC; i += 256) sm.g2.wsm[i] = W2[i];
        __syncthreads();
        int nga = (n + 31) >> 5;
        for (int g = blockIdx.x; g < nga; g += GRID)
            agg2_tile(sm.g2, g, row_start, es, dinv, hbu, b2, out, n, t);
    }
}

// ================= fallback standalone kernels (round-10 pipeline) =================
__global__ __launch_bounds__(256) void k_bin0(
    const int* __restrict__ srcs, const int* __restrict__ dsts,
    int* __restrict__ gcur, uint_t* __restrict__ tmp, int e,
    const float* __restrict__ W1, ushort_t* __restrict__ Wp,
    ushort_t* __restrict__ hb, int n)
{
    __shared__ SmBin smb;
    int nchunk = (e + BCH - 1) / BCH;
    if ((int)blockIdx.x >= nchunk) { side_work(W1, Wp, hb, n, threadIdx.x); return; }
    bin_chunk(smb, blockIdx.x, srcs, dsts, gcur, tmp, e, threadIdx.x);
}

__global__ __launch_bounds__(256) void k_sort(
    const uint_t* __restrict__ tmp, const int* __restrict__ gcur,
    int* __restrict__ row_start, float* __restrict__ dinv,
    uint_t* __restrict__ es, int n, int e)
{
    __shared__ SmSort sms;
    sort_bucket(sms, blockIdx.x, tmp, gcur, row_start, dinv, es, n, e, threadIdx.x);
}

__global__ __launch_bounds__(256) void k_gemm1(
    const float* __restrict__ x, const ushort_t* __restrict__ Wp,
    const float* __restrict__ dinv, ushort_t* __restrict__ hw1, int n)
{
    gemm1_tile(blockIdx.x, x, Wp, dinv, hw1, n, threadIdx.x);
}

__global__ __launch_bounds__(256, 4) void k_agg1(
    const int* __restrict__ row_start, const uint_t* __restrict__ es,
    const float* __restrict__ dinv, const uint_t* __restrict__ hw1u,
    const float* __restrict__ b1, ushort_t* __restrict__ hb, int n)
{
    agg1_tile(blockIdx.x, row_start, es, dinv, hw1u, b1, hb, n, threadIdx.x);
}

__global__ __launch_bounds__(256, 4) void k_agg2(
    const int* __restrict__ row_start, const uint_t* __restrict__ es,
    const float* __restrict__ dinv, const uint_t* __restrict__ hbu,
    const float* __restrict__ W2, const float* __restrict__ b2,
    float* __restrict__ out, int n)
{
    __shared__ SmG2 smg;
    for (int i = threadIdx.x; i < HID * NC; i += 256) smg.wsm[i] = W2[i];
    __syncthreads();
    agg2_tile(smg, blockIdx.x, row_start, es, dinv, hbu, b2, out, n, threadIdx.x);
}

extern "C" void kernel_launch(void* const* d_in, const int* in_sizes, int n_in,
                              void* d_out, int out_size, void* d_ws, size_t ws_size,
                              hipStream_t stream) {
    const float* x  = (const float*)d_in[0];   // f32 [N,128]
    const int* edge = (const int*)d_in[1];     // int32 [2,E]
    const float* W1 = (const float*)d_in[2];   // f32 [128,64]
    const float* b1 = (const float*)d_in[3];   // f32 [64]
    const float* W2 = (const float*)d_in[4];   // f32 [64,40]
    const float* b2 = (const float*)d_in[5];   // f32 [40]
    float* out      = (float*)d_out;           // f32 [N,40]

    int n = in_sizes[0] / IN_CH;   // 100000
    int e = in_sizes[1] / 2;       // 1600000
    const int* srcs = edge;
    const int* dsts = edge + e;

    // workspace layout (all segments 16B-aligned)
    int*      gcur      = (int*)d_ws;                       // 196 cursors (256 reserved)
    int*      row_start = gcur + 256;                       // NPAD (needs n+1)
    float*    dinv      = (float*)(row_start + NPAD);       // NPAD
    uint_t*   tmp       = (uint_t*)(dinv + NPAD);           // NBUK*CAP packed 4B
    uint_t*   es        = tmp + (size_t)NBUK * CAP;         // NEDGES src-only 4B
    ushort_t* Wp        = (ushort_t*)(es + NEDGES);         // 8192 bf16
    ushort_t* hw1       = Wp + 8192;                        // (N+1)*64 bf16 (sentinel row n)
    ushort_t* hb        = hw1 + (size_t)(NNODES + 1) * HID; // (N+1)*64 bf16 (sentinel row n)

    hipMemsetAsync(gcur, 0, 256 * sizeof(int), stream);     // count-only cursors

    // try the fused cooperative pipeline; on ANY error fall back to the
    // verified 5-kernel pipeline (identical phase bodies)
    void* args[] = {
        (void*)&srcs, (void*)&dsts, (void*)&gcur, (void*)&tmp,
        (void*)&W1, (void*)&Wp, (void*)&hb,
        (void*)&row_start, (void*)&dinv, (void*)&es,
        (void*)&x, (void*)&hw1, (void*)&b1,
        (void*)&W2, (void*)&b2, (void*)&out,
        (void*)&n, (void*)&e
    };
    hipError_t err = hipLaunchCooperativeKernel((void*)k_all, dim3(GRID), dim3(256),
                                                args, 0, stream);
    if (err != hipSuccess) {
        (void)hipGetLastError();   // clear sticky error
        int nchunk = (e + BCH - 1) / BCH;
        k_bin0<<<nchunk + 1, 256, 0, stream>>>(srcs, dsts, gcur, tmp, e, W1, Wp, hb, n);
        k_sort<<<NBUK, 256, 0, stream>>>(tmp, gcur, row_start, dinv, es, n, e);
        k_gemm1<<<(n + 63) / 64, 256, 0, stream>>>(x, Wp, dinv, hw1, n);
        k_agg1<<<(n + 31) / 32, 256, 0, stream>>>(row_start, es, dinv, (const uint_t*)hw1, b1, hb, n);
        k_agg2<<<(n + 31) / 32, 256, 0, stream>>>(row_start, es, dinv, (const uint_t*)hb, W2, b2, out, n);
    }
}

// Round 14
// 214.405 us; speedup vs baseline: 3.2557x; 3.2557x over previous
//
#include <hip/hip_runtime.h>
#include <hip/hip_bf16.h>

#define NNODES 100000
#define NEDGES 1600000
#define IN_CH 128
#define HID 64
#define NC 40
#define NPAD 100352   // NNODES padded to multiple of 256
#define NBUK 196      // ceil(100000 / 512) dst-buckets of 512 nodes
#define CAP 9216      // per-bucket tmp capacity (mean 8192, sigma ~90 -> 11 sigma)
#define BCHUNK 4096
#define NBIN 391      // ceil(NEDGES / BCHUNK)

typedef unsigned short ushort_t;
typedef unsigned int uint_t;
typedef __attribute__((ext_vector_type(8))) short short8;
typedef __attribute__((ext_vector_type(4))) float floatx4;
typedef __attribute__((ext_vector_type(2))) float f32x2;

__device__ __forceinline__ ushort_t f2bf(float f) {
    union { float ff; unsigned int i; } t;
    t.ff = f;
    unsigned int r = t.i + 0x7fff + ((t.i >> 16) & 1);  // RNE
    return (ushort_t)(r >> 16);
}
// acc += w * unpack(packed bf16x2)
__device__ __forceinline__ void acc2w(f32x2& a, uint_t p, float w) {
    union { unsigned int i; float f; } lo, hi;
    lo.i = p << 16;
    hi.i = p & 0xffff0000u;
    a.x += lo.f * w;
    a.y += hi.f * w;
}
// acc += unpack(packed bf16x2)
__device__ __forceinline__ void acc2(f32x2& a, uint_t p) {
    union { unsigned int i; float f; } lo, hi;
    lo.i = p << 16;
    hi.i = p & 0xffff0000u;
    f32x2 v = {lo.f, hi.f};
    a += v;
}

// ---- merged bin + GEMM1 kernel ----
// blocks 0..NBIN-1 : bin edges into bucket-major tmp (LDS bucket sort ->
//                    coalesced write-out)
// block NBIN       : hb zero-sentinel only
// blocks NBIN+1..  : GEMM1 tiles, hw1 = bf16(x @ W1) UNSCALED. Each gemm1
//                    block swizzles W1 -> LDS ITSELF (round-13 bug: reading a
//                    Wp written by another block of the same dispatch raced —
//                    dispatch order undefined). No cross-block deps remain.
__global__ __launch_bounds__(256) void k_bg(
    const int* __restrict__ srcs, const int* __restrict__ dsts,
    int* __restrict__ gcur, uint_t* __restrict__ tmp, int e,
    const float* __restrict__ W1, ushort_t* __restrict__ hb,
    const float* __restrict__ x, ushort_t* __restrict__ hw1, int n)
{
    __shared__ uint_t pk[BCHUNK];    // 16 KB (bin: input order | gemm1: Wp swizzle)
    __shared__ ushort_t bk[BCHUNK];  // 8 KB
    __shared__ uint_t spk[BCHUNK];   // 16 KB (bucket-sorted)
    __shared__ ushort_t sb[BCHUNK];  // 8 KB bucket id per sorted slot
    __shared__ int hist[NBUK];
    __shared__ int lscan[NBUK];
    __shared__ int base[NBUK];
    __shared__ int sc2[256];
    int t = threadIdx.x;

    if ((int)blockIdx.x > NBIN) {
        // ---------------- GEMM1 tile (W1 swizzled into own LDS) ----------------
        ushort_t* wl = (ushort_t*)pk;   // 8192 bf16 = 16 KB, aliases bin LDS
        for (int i = t; i < IN_CH * HID; i += 256) {
            int j = i & 7;
            int m = (i >> 3) & 15;
            int ct = (i >> 7) & 3;
            int quad = (i >> 9) & 3;
            int kc = i >> 11;
            int k = kc * 32 + quad * 8 + j;
            int c = ct * 16 + m;
            wl[i] = f2bf(W1[k * HID + c]);
        }
        __syncthreads();
        int blk = blockIdx.x - (NBIN + 1);
        int wave = t >> 6;
        int lane = t & 63;
        int m = lane & 15;
        int quad = lane >> 4;
        int row = blk * 64 + wave * 16 + m;
        int rowc = row < n ? row : (n - 1);
        const float* xr = x + (size_t)rowc * IN_CH + quad * 8;
        floatx4 acc[4];
#pragma unroll
        for (int ct = 0; ct < 4; ++ct) acc[ct] = (floatx4){0.f, 0.f, 0.f, 0.f};
#pragma unroll
        for (int kc = 0; kc < 4; ++kc) {
            float4 xa = *(const float4*)(xr + kc * 32);
            float4 xb = *(const float4*)(xr + kc * 32 + 4);
            short8 a;
            a[0] = (short)f2bf(xa.x); a[1] = (short)f2bf(xa.y);
            a[2] = (short)f2bf(xa.z); a[3] = (short)f2bf(xa.w);
            a[4] = (short)f2bf(xb.x); a[5] = (short)f2bf(xb.y);
            a[6] = (short)f2bf(xb.z); a[7] = (short)f2bf(xb.w);
#pragma unroll
            for (int ct = 0; ct < 4; ++ct) {
                short8 bfr = *(const short8*)(wl + ((((kc * 4 + quad) * 4 + ct) * 16 + m) << 3));
                acc[ct] = __builtin_amdgcn_mfma_f32_16x16x32_bf16(a, bfr, acc[ct], 0, 0, 0);
            }
        }
        int r0 = blk * 64 + wave * 16 + quad * 4;
#pragma unroll
        for (int r = 0; r < 4; ++r) {
            int rr = r0 + r;
            if (rr < n) {
                ushort_t* o = hw1 + (size_t)rr * HID + m;
#pragma unroll
                for (int ct = 0; ct < 4; ++ct) o[ct * 16] = f2bf(acc[ct][r]);
            } else if (rr == n) {
                ushort_t* o = hw1 + (size_t)n * HID + m;
#pragma unroll
                for (int ct = 0; ct < 4; ++ct) o[ct * 16] = 0;
            }
        }
        return;
    }
    if ((int)blockIdx.x == NBIN) {   // side-work: hb zero-sentinel only
        uint_t* hbz = (uint_t*)(hb + (size_t)n * HID);
        if (t < 32) hbz[t] = 0;      // 64 bf16 zeros (sentinel row n)
        return;
    }
    // ---------------- bin chunk ----------------
    int begin = blockIdx.x * BCHUNK;
    int cnt = e - begin; if (cnt > BCHUNK) cnt = BCHUNK;
    for (int i = t; i < NBUK; i += 256) hist[i] = 0;
    __syncthreads();
    for (int j = t; j < cnt; j += 256) {
        int d = dsts[begin + j];
        int s = srcs[begin + j];
        int b = d >> 9;
        pk[j] = (uint_t)s | ((uint_t)(d & 511) << 17);
        bk[j] = (ushort_t)b;
        atomicAdd(&hist[b], 1);
    }
    __syncthreads();
    int c = (t < NBUK) ? hist[t] : 0;
    sc2[t] = c;
    __syncthreads();
    for (int off = 1; off < 256; off <<= 1) {
        int v = (t >= off) ? sc2[t - off] : 0;
        __syncthreads();
        sc2[t] += v;
        __syncthreads();
    }
    if (t < NBUK) {
        lscan[t] = sc2[t] - c;
        base[t] = t * CAP + atomicAdd(&gcur[t], c);
        hist[t] = 0;                 // reuse as rank cursor
    }
    __syncthreads();
    for (int j = t; j < cnt; j += 256) {
        int b = bk[j];
        int r = atomicAdd(&hist[b], 1);
        int slot = lscan[b] + r;
        spk[slot] = pk[j];
        sb[slot] = (ushort_t)b;
    }
    __syncthreads();
    for (int j = t; j < cnt; j += 256) {
        int b = sb[j];
        int pos = base[b] + (j - lscan[b]);
        if (pos < (b + 1) * CAP) tmp[pos] = spk[j];  // guard vs overflow
    }
}

// ---- merged sort: per-bucket count + scan + row_start/dinv + scatter to es ----
// LDS-staged es write-out (coalesced). row_start written unconditionally
// (node n's start = e naturally); dinv[node>=n] = 0 so the sentinel's
// gathered weight is exactly 0 (never NaN).
__global__ __launch_bounds__(256) void k_sort(
    const uint_t* __restrict__ tmp, const int* __restrict__ gcur,
    int* __restrict__ row_start, float* __restrict__ dinv,
    uint_t* __restrict__ es, int n, int e)
{
    __shared__ int cnt[512];
    __shared__ int sc[512];
    __shared__ int red[256];
    __shared__ uint_t esl[CAP];   // 36 KB staging (total <= CAP)
    int t = threadIdx.x;
    int b = blockIdx.x;
    int d0 = b << 9;
    int total = gcur[b];
    if (total > CAP) total = CAP;
    int part = 0;
    for (int i = t; i < b; i += 256) part += gcur[i];
    red[t] = part;
    cnt[t] = 0; cnt[t + 256] = 0;
    __syncthreads();
    for (int off = 128; off > 0; off >>= 1) {
        if (t < off) red[t] += red[t + off];
        __syncthreads();
    }
    int gb = red[0];
    const uint_t* seg = tmp + b * CAP;
    for (int j = t; j < total; j += 256)
        atomicAdd(&cnt[seg[j] >> 17], 1);
    __syncthreads();
    sc[t] = cnt[t]; sc[t + 256] = cnt[t + 256];
    __syncthreads();
    for (int off = 1; off < 512; off <<= 1) {
        int v0 = (t >= off) ? sc[t - off] : 0;
        int i1 = t + 256;
        int v1 = (i1 >= off) ? sc[i1 - off] : 0;
        __syncthreads();
        sc[t] += v0; sc[i1] += v1;
        __syncthreads();
    }
#pragma unroll
    for (int q = 0; q < 2; ++q) {
        int i = t + q * 256;
        int node = d0 + i;
        int start = gb + sc[i] - cnt[i];
        row_start[node] = start;                  // node n gets e naturally
        dinv[node] = (node < n) ? rsqrtf((float)cnt[i] + 1.0f) : 0.f;
        cnt[i] = start - gb;   // local scatter cursor (segment-relative)
    }
    __syncthreads();
    for (int j = t; j < total; j += 256) {
        uint_t p = seg[j];
        int ld = (int)(p >> 17);
        int pos = atomicAdd(&cnt[ld], 1);
        esl[pos] = p & 0x1FFFFu;
    }
    __syncthreads();
    for (int j = t; j < total; j += 256) es[gb + j] = esl[j];
}

// ---- agg1: octet per node; weighted gather (w = dinv[s] from L2-resident
// dinv, shfl-broadcast alongside the index); epilogue stores hb = bf16(h*di).
// hw1 is UNSCALED; sentinel el=n has dinv[n]=0 -> contributes exactly 0.
__global__ __launch_bounds__(256, 4) void k_agg1(
    const int* __restrict__ row_start, const uint_t* __restrict__ es,
    const float* __restrict__ dinv, const uint_t* __restrict__ hw1u,
    const float* __restrict__ b1, ushort_t* __restrict__ hb, int n)
{
    int lane = threadIdx.x & 63;
    int obase = lane & 56;              // octet's first lane in the wave
    int ol = lane & 7;
    int node = blockIdx.x * 32 + (threadIdx.x >> 3);
    bool valid = node < n;
    int rs = valid ? row_start[node] : 0;
    int re = valid ? row_start[node + 1] : 0;
    float di = valid ? dinv[node] : 0.f;
    int selfrow = valid ? node : n;

    f32x2 c0, c1, c2, c3;
    {
        uint4 sp = *(const uint4*)(hw1u + (size_t)selfrow * 32 + ol * 4);
        c0 = (f32x2){0.f, 0.f}; c1 = c0; c2 = c0; c3 = c0;
        acc2w(c0, sp.x, di); acc2w(c1, sp.y, di);
        acc2w(c2, sp.z, di); acc2w(c3, sp.w, di);
    }
    int el = n; float dv = 0.f;
    if (rs < re) {
        int idx = rs + ol;
        el = (idx < re) ? (int)es[idx] : n;   // pad -> zero sentinel
        dv = dinv[el];                        // dinv[n] == 0
    }
    for (int base = rs; base < re; base += 8) {
        int el_cur = el; float dv_cur = dv;
        int nb = base + 8;
        if (nb < re) {                         // prefetch next window
            int idx = nb + ol;
            el = (idx < re) ? (int)es[idx] : n;
            dv = dinv[el];
        }
        uint4 p[8]; float w[8];
#pragma unroll
        for (int b = 0; b < 8; ++b) {
            int s = __shfl(el_cur, obase + b);
            w[b] = __shfl(dv_cur, obase + b);
            p[b] = *(const uint4*)(hw1u + (size_t)s * 32 + ol * 4);
        }
#pragma unroll
        for (int b = 0; b < 8; ++b) {
            acc2w(c0, p[b].x, w[b]); acc2w(c1, p[b].y, w[b]);
            acc2w(c2, p[b].z, w[b]); acc2w(c3, p[b].w, w[b]);
        }
    }
    if (valid) {
        float4 bb0 = ((const float4*)b1)[ol * 2];
        float4 bb1 = ((const float4*)b1)[ol * 2 + 1];
        float h0 = fmaxf(c0.x * di + bb0.x, 0.f);
        float h1 = fmaxf(c0.y * di + bb0.y, 0.f);
        float h2 = fmaxf(c1.x * di + bb0.z, 0.f);
        float h3 = fmaxf(c1.y * di + bb0.w, 0.f);
        float h4 = fmaxf(c2.x * di + bb1.x, 0.f);
        float h5 = fmaxf(c2.y * di + bb1.y, 0.f);
        float h6 = fmaxf(c3.x * di + bb1.z, 0.f);
        float h7 = fmaxf(c3.y * di + bb1.w, 0.f);
        // hb = dinv * h (source weight pre-folded for layer-2), bf16-packed
        uint4 st;
        st.x = (uint_t)f2bf(h0 * di) | ((uint_t)f2bf(h1 * di) << 16);
        st.y = (uint_t)f2bf(h2 * di) | ((uint_t)f2bf(h3 * di) << 16);
        st.z = (uint_t)f2bf(h4 * di) | ((uint_t)f2bf(h5 * di) << 16);
        st.w = (uint_t)f2bf(h6 * di) | ((uint_t)f2bf(h7 * di) << 16);
        *(uint4*)(hb + (size_t)node * HID + ol * 8) = st;
    }
}

// ---- agg2 + fused GEMM2: octet gather over hb (pre-scaled) + same-wave LDS dot ----
__global__ __launch_bounds__(256, 4) void k_agg2(
    const int* __restrict__ row_start, const uint_t* __restrict__ es,
    const float* __restrict__ dinv, const uint_t* __restrict__ hbu,
    const float* __restrict__ W2, const float* __restrict__ b2,
    float* __restrict__ out, int n)
{
    __shared__ float wsm[HID * NC];   // 10 KB, W2 row-major [64][40]
    __shared__ float hsm[32][68];     // 32 nodes x 64ch (+pad)
    for (int i = threadIdx.x; i < HID * NC; i += 256) wsm[i] = W2[i];
    __syncthreads();

    int lane = threadIdx.x & 63;
    int obase = lane & 56;
    int ol = lane & 7;
    int slot = threadIdx.x >> 3;        // node slot within block (0..31)
    int node = blockIdx.x * 32 + slot;
    bool valid = node < n;
    int rs = valid ? row_start[node] : 0;
    int re = valid ? row_start[node + 1] : 0;
    float di = valid ? dinv[node] : 0.f;
    int selfrow = valid ? node : n;

    f32x2 c0, c1, c2, c3;
    {
        uint4 sp = *(const uint4*)(hbu + (size_t)selfrow * 32 + ol * 4);
        c0 = (f32x2){0.f, 0.f}; c1 = c0; c2 = c0; c3 = c0;
        acc2(c0, sp.x); acc2(c1, sp.y); acc2(c2, sp.z); acc2(c3, sp.w);
    }
    int el = n;
    if (rs < re) {
        int idx = rs + ol;
        el = (idx < re) ? (int)es[idx] : n;   // pad -> zero sentinel
    }
    for (int base = rs; base < re; base += 8) {
        int el_cur = el;
        int nb = base + 8;
        if (nb < re) {                         // prefetch next window
            int idx = nb + ol;
            el = (idx < re) ? (int)es[idx] : n;
        }
        uint4 p[8];
#pragma unroll
        for (int b = 0; b < 8; ++b) {
            int s = __shfl(el_cur, obase + b);
            p[b] = *(const uint4*)(hbu + (size_t)s * 32 + ol * 4);
        }
#pragma unroll
        for (int b = 0; b < 8; ++b) {
            acc2(c0, p[b].x); acc2(c1, p[b].y);
            acc2(c2, p[b].z); acc2(c3, p[b].w);
        }
    }
    // hagg row (f32) -> LDS; garbage for invalid nodes (never stored to out)
    {
        float4 g0, g1;
        g0.x = c0.x * di; g0.y = c0.y * di; g0.z = c1.x * di; g0.w = c1.y * di;
        g1.x = c2.x * di; g1.y = c2.y * di; g1.z = c3.x * di; g1.w = c3.y * di;
        *(float4*)&hsm[slot][ol * 8] = g0;
        *(float4*)&hsm[slot][ol * 8 + 4] = g1;
    }
    // fused GEMM2: two passes of 4-node quarter-wave dot over the wave's rows
    int w8 = (threadIdx.x >> 6) * 8;    // wave's first slot
    int qm = lane >> 4;                 // quarter 0..3
    int lq = lane & 15;
    int lw = (lq < 10) ? lq : 0;
    const float4* w4 = (const float4*)wsm;     // [64][10] float4
#pragma unroll
    for (int pass = 0; pass < 2; ++pass) {
        int slot2 = w8 + pass * 4 + qm;
        int node2 = blockIdx.x * 32 + slot2;
        float4 acc = ((const float4*)b2)[lw];  // b2 as accumulator init
#pragma unroll 4
        for (int k4 = 0; k4 < 16; ++k4) {
            float4 hk = *(const float4*)&hsm[slot2][k4 * 4];
            float4 w0 = w4[(k4 * 4 + 0) * 10 + lw];
            float4 w1 = w4[(k4 * 4 + 1) * 10 + lw];
            float4 w2 = w4[(k4 * 4 + 2) * 10 + lw];
            float4 w3 = w4[(k4 * 4 + 3) * 10 + lw];
            acc.x += hk.x * w0.x + hk.y * w1.x + hk.z * w2.x + hk.w * w3.x;
            acc.y += hk.x * w0.y + hk.y * w1.y + hk.z * w2.y + hk.w * w3.y;
            acc.z += hk.x * w0.z + hk.y * w1.z + hk.z * w2.z + hk.w * w3.z;
            acc.w += hk.x * w0.w + hk.y * w1.w + hk.z * w2.w + hk.w * w3.w;
        }
        if (node2 < n && lq < 10)
            *(float4*)(out + (size_t)node2 * NC + lq * 4) = acc;
    }
}

extern "C" void kernel_launch(void* const* d_in, const int* in_sizes, int n_in,
                              void* d_out, int out_size, void* d_ws, size_t ws_size,
                              hipStream_t stream) {
    const float* x  = (const float*)d_in[0];   // f32 [N,128]
    const int* edge = (const int*)d_in[1];     // int32 [2,E]
    const float* W1 = (const float*)d_in[2];   // f32 [128,64]
    const float* b1 = (const float*)d_in[3];   // f32 [64]
    const float* W2 = (const float*)d_in[4];   // f32 [64,40]
    const float* b2 = (const float*)d_in[5];   // f32 [40]
    float* out      = (float*)d_out;           // f32 [N,40]

    const int n = in_sizes[0] / IN_CH;   // 100000
    const int e = in_sizes[1] / 2;       // 1600000
    const int* srcs = edge;
    const int* dsts = edge + e;

    // workspace layout (all segments 16B-aligned)
    int*      gcur      = (int*)d_ws;                       // 196 cursors (256 reserved)
    int*      row_start = gcur + 256;                       // NPAD (needs n+1)
    float*    dinv      = (float*)(row_start + NPAD);       // NPAD
    uint_t*   tmp       = (uint_t*)(dinv + NPAD);           // NBUK*CAP packed 4B
    uint_t*   es        = tmp + (size_t)NBUK * CAP;         // NEDGES src-only 4B
    ushort_t* hw1       = (ushort_t*)(es + NEDGES);         // (N+1)*64 bf16 (sentinel row n)
    ushort_t* hb        = hw1 + (size_t)(NNODES + 1) * HID; // (N+1)*64 bf16 (sentinel row n)

    const int ng1 = (n + 63) / 64;       // gemm1 tiles

    hipMemsetAsync(gcur, 0, NBUK * sizeof(int), stream);    // count-only cursors
    k_bg<<<NBIN + 1 + ng1, 256, 0, stream>>>(srcs, dsts, gcur, tmp, e, W1, hb, x, hw1, n);
    k_sort<<<NBUK, 256, 0, stream>>>(tmp, gcur, row_start, dinv, es, n, e);
    k_agg1<<<(n + 31) / 32, 256, 0, stream>>>(row_start, es, dinv, (const uint_t*)hw1, b1, hb, n);
    k_agg2<<<(n + 31) / 32, 256, 0, stream>>>(row_start, es, dinv, (const uint_t*)hb, W2, b2, out, n);
}

// Round 15
// 212.313 us; speedup vs baseline: 3.2878x; 1.0099x over previous
//
#include <hip/hip_runtime.h>
#include <hip/hip_bf16.h>

#define NNODES 100000
#define NEDGES 1600000
#define IN_CH 128
#define HID 64
#define NC 40
#define NPAD 100352   // NNODES padded to multiple of 256
#define NBUK 196      // ceil(100000 / 512) dst-buckets of 512 nodes
#define CAP 9216      // per-bucket tmp capacity (mean 8192, sigma ~90 -> 11 sigma)
#define BCHUNK 4096
#define NBIN 391      // ceil(NEDGES / BCHUNK)

typedef unsigned short ushort_t;
typedef unsigned int uint_t;
typedef __attribute__((ext_vector_type(8))) short short8;
typedef __attribute__((ext_vector_type(4))) float floatx4;
typedef __attribute__((ext_vector_type(2))) float f32x2;

__device__ __forceinline__ ushort_t f2bf(float f) {
    union { float ff; unsigned int i; } t;
    t.ff = f;
    unsigned int r = t.i + 0x7fff + ((t.i >> 16) & 1);  // RNE
    return (ushort_t)(r >> 16);
}
// acc += unpack(packed bf16x2); vector += encourages v_pk_add_f32
__device__ __forceinline__ void acc2(f32x2& a, uint_t p) {
    union { unsigned int i; float f; } lo, hi;
    lo.i = p << 16;
    hi.i = p & 0xffff0000u;
    f32x2 v = {lo.f, hi.f};
    a += v;
}

// ---- bin edges into bucket-major tmp; entry: src(17b) | local_d(9b)<<17 ----
// gcur is count-only (zeroed by hipMemsetAsync); segment base = b*CAP + count.
// Block-local bucket sort in LDS before write-out, so tmp stores are
// contiguous runs per bucket (round-8 PMC: scattered 4B stores cost 58 MB
// WRITE_SIZE for 6.4 MB of data -> ~9x write amplification).
// Extra block (blockIdx == NBIN): Wp swizzle + hb zero-sentinel (row n).
__global__ __launch_bounds__(256) void k_bin0(
    const int* __restrict__ srcs, const int* __restrict__ dsts,
    int* __restrict__ gcur, uint_t* __restrict__ tmp, int e,
    const float* __restrict__ W1, ushort_t* __restrict__ Wp,
    ushort_t* __restrict__ hb, int n)
{
    __shared__ uint_t pk[BCHUNK];    // 16 KB (input order)
    __shared__ ushort_t bk[BCHUNK];  // 8 KB
    __shared__ uint_t spk[BCHUNK];   // 16 KB (bucket-sorted)
    __shared__ ushort_t sb[BCHUNK];  // 8 KB bucket id per sorted slot
    __shared__ int hist[NBUK];
    __shared__ int lscan[NBUK];      // local exclusive scan over buckets
    __shared__ int base[NBUK];       // global base per bucket
    __shared__ int sc2[256];
    int t = threadIdx.x;
    if (blockIdx.x >= NBIN) {        // side-work block (uniform branch)
        for (int i = t; i < IN_CH * HID; i += 256) {
            int j = i & 7;
            int m = (i >> 3) & 15;
            int ct = (i >> 7) & 3;
            int quad = (i >> 9) & 3;
            int kc = i >> 11;
            int k = kc * 32 + quad * 8 + j;
            int c = ct * 16 + m;
            Wp[i] = f2bf(W1[k * HID + c]);
        }
        uint_t* hbz = (uint_t*)(hb + (size_t)n * HID);
        if (t < 32) hbz[t] = 0;      // 64 bf16 zeros (sentinel row n)
        return;
    }
    int begin = blockIdx.x * BCHUNK;
    int cnt = e - begin; if (cnt > BCHUNK) cnt = BCHUNK;

    for (int i = t; i < NBUK; i += 256) hist[i] = 0;
    __syncthreads();
    // pass 1: load + per-bucket count
    for (int j = t; j < cnt; j += 256) {
        int d = dsts[begin + j];
        int s = srcs[begin + j];
        int b = d >> 9;
        pk[j] = (uint_t)s | ((uint_t)(d & 511) << 17);
        bk[j] = (ushort_t)b;
        atomicAdd(&hist[b], 1);
    }
    __syncthreads();
    // pass 2: local scan (196 buckets) + global segment reservation
    int c = (t < NBUK) ? hist[t] : 0;
    sc2[t] = c;
    __syncthreads();
    for (int off = 1; off < 256; off <<= 1) {
        int v = (t >= off) ? sc2[t - off] : 0;
        __syncthreads();
        sc2[t] += v;
        __syncthreads();
    }
    if (t < NBUK) {
        lscan[t] = sc2[t] - c;
        base[t] = t * CAP + atomicAdd(&gcur[t], c);
        hist[t] = 0;                 // reuse as rank cursor
    }
    __syncthreads();
    // pass 3: rank-scatter into sorted LDS buffer
    for (int j = t; j < cnt; j += 256) {
        int b = bk[j];
        int r = atomicAdd(&hist[b], 1);
        int slot = lscan[b] + r;
        spk[slot] = pk[j];
        sb[slot] = (ushort_t)b;
    }
    __syncthreads();
    // pass 4: linear write-out (contiguous run per bucket)
    for (int j = t; j < cnt; j += 256) {
        int b = sb[j];
        int pos = base[b] + (j - lscan[b]);
        if (pos < (b + 1) * CAP) tmp[pos] = spk[j];  // guard vs overflow
    }
}

// ---- merged sort: per-bucket count + scan + row_start/dinv + scatter to es ----
// Scatter to LDS staging (block's whole output segment), then fully
// coalesced linear copy to es (kills the random-4B-store write amplification).
__global__ __launch_bounds__(256) void k_sort(
    const uint_t* __restrict__ tmp, const int* __restrict__ gcur,
    int* __restrict__ row_start, float* __restrict__ dinv,
    uint_t* __restrict__ es, int n, int e)
{
    __shared__ int cnt[512];
    __shared__ int sc[512];
    __shared__ int red[256];
    __shared__ uint_t esl[CAP];   // 36 KB staging (total <= CAP)
    int t = threadIdx.x;
    int b = blockIdx.x;
    int d0 = b << 9;
    int total = gcur[b];
    if (total > CAP) total = CAP;
    // gb = exclusive prefix over bucket totals
    int part = 0;
    for (int i = t; i < b; i += 256) part += gcur[i];
    red[t] = part;
    cnt[t] = 0; cnt[t + 256] = 0;
    __syncthreads();
    for (int off = 128; off > 0; off >>= 1) {
        if (t < off) red[t] += red[t + off];
        __syncthreads();
    }
    int gb = red[0];
    // count per node
    const uint_t* seg = tmp + b * CAP;
    for (int j = t; j < total; j += 256)
        atomicAdd(&cnt[seg[j] >> 17], 1);
    __syncthreads();
    sc[t] = cnt[t]; sc[t + 256] = cnt[t + 256];
    __syncthreads();
    for (int off = 1; off < 512; off <<= 1) {
        int v0 = (t >= off) ? sc[t - off] : 0;
        int i1 = t + 256;
        int v1 = (i1 >= off) ? sc[i1 - off] : 0;
        __syncthreads();
        sc[t] += v0; sc[i1] += v1;
        __syncthreads();
    }
#pragma unroll
    for (int q = 0; q < 2; ++q) {
        int i = t + q * 256;
        int node = d0 + i;
        int start = gb + sc[i] - cnt[i];
        if (node < n) {
            row_start[node] = start;
            dinv[node] = rsqrtf((float)cnt[i] + 1.0f);
        }
        cnt[i] = start - gb;   // reuse cnt as LOCAL scatter cursor (segment-relative)
    }
    __syncthreads();
    // scatter to LDS staging in final CSR order
    for (int j = t; j < total; j += 256) {
        uint_t p = seg[j];
        int ld = (int)(p >> 17);
        int pos = atomicAdd(&cnt[ld], 1);
        esl[pos] = p & 0x1FFFFu;
    }
    __syncthreads();
    // coalesced linear write-out
    for (int j = t; j < total; j += 256) es[gb + j] = esl[j];
    if (b == NBUK - 1 && t == 0) row_start[n] = e;
}

// ---- GEMM1: hw1 = bf16(dinv * (x @ W1)) via MFMA; row n = zero sentinel ----
__global__ __launch_bounds__(256) void k_gemm1(
    const float* __restrict__ x, const ushort_t* __restrict__ Wp,
    const float* __restrict__ dinv, ushort_t* __restrict__ hw1, int n)
{
    int wave = threadIdx.x >> 6;
    int lane = threadIdx.x & 63;
    int m = lane & 15;
    int quad = lane >> 4;
    int row = blockIdx.x * 64 + wave * 16 + m;
    int rowc = row < n ? row : (n - 1);
    const float* xr = x + (size_t)rowc * IN_CH + quad * 8;

    floatx4 acc[4];
#pragma unroll
    for (int ct = 0; ct < 4; ++ct) acc[ct] = (floatx4){0.f, 0.f, 0.f, 0.f};

#pragma unroll
    for (int kc = 0; kc < 4; ++kc) {
        float4 xa = *(const float4*)(xr + kc * 32);
        float4 xb = *(const float4*)(xr + kc * 32 + 4);
        short8 a;
        a[0] = (short)f2bf(xa.x); a[1] = (short)f2bf(xa.y);
        a[2] = (short)f2bf(xa.z); a[3] = (short)f2bf(xa.w);
        a[4] = (short)f2bf(xb.x); a[5] = (short)f2bf(xb.y);
        a[6] = (short)f2bf(xb.z); a[7] = (short)f2bf(xb.w);
#pragma unroll
        for (int ct = 0; ct < 4; ++ct) {
            short8 b = *(const short8*)(Wp + ((((kc * 4 + quad) * 4 + ct) * 16 + m) << 3));
            acc[ct] = __builtin_amdgcn_mfma_f32_16x16x32_bf16(a, b, acc[ct], 0, 0, 0);
        }
    }
    int r0 = blockIdx.x * 64 + wave * 16 + quad * 4;
#pragma unroll
    for (int r = 0; r < 4; ++r) {
        int rr = r0 + r;
        if (rr < n) {
            float di = dinv[rr];
            ushort_t* o = hw1 + (size_t)rr * HID + m;
#pragma unroll
            for (int ct = 0; ct < 4; ++ct) o[ct * 16] = f2bf(acc[ct][r] * di);
        } else if (rr == n) {
            ushort_t* o = hw1 + (size_t)n * HID + m;
#pragma unroll
            for (int ct = 0; ct < 4; ++ct) o[ct * 16] = 0;
        }
    }
}

// ---- agg1: one OCTET (8 lanes) per node ----
// __launch_bounds__(256,4) + es-prefetch (round-10 best). Row = 64ch bf16 =
// 128 B = 8 lanes x dwordx4; one gather fetches 8 rows; 8 node-chains/wave.
// Uniform 8-edge windows: sentinel row n (all zero) absorbs padding.
__global__ __launch_bounds__(256, 4) void k_agg1(
    const int* __restrict__ row_start, const uint_t* __restrict__ es,
    const float* __restrict__ dinv, const uint_t* __restrict__ hw1u,
    const float* __restrict__ b1, ushort_t* __restrict__ hb, int n)
{
    int lane = threadIdx.x & 63;
    int obase = lane & 56;              // octet's first lane in the wave
    int ol = lane & 7;
    int node = blockIdx.x * 32 + (threadIdx.x >> 3);
    bool valid = node < n;
    int rs = valid ? row_start[node] : 0;
    int re = valid ? row_start[node + 1] : 0;
    float di = valid ? dinv[node] : 0.f;
    int selfrow = valid ? node : n;

    f32x2 c0, c1, c2, c3;
    {
        uint4 sp = *(const uint4*)(hw1u + (size_t)selfrow * 32 + ol * 4);
        c0 = (f32x2){0.f, 0.f}; c1 = c0; c2 = c0; c3 = c0;
        acc2(c0, sp.x); acc2(c1, sp.y); acc2(c2, sp.z); acc2(c3, sp.w);
    }
    int el = n;
    if (rs < re) {
        int idx = rs + ol;
        el = (idx < re) ? (int)es[idx] : n;   // pad -> zero sentinel
    }
    for (int base = rs; base < re; base += 8) {
        int el_cur = el;
        int nb = base + 8;
        if (nb < re) {                         // prefetch next window's indices
            int idx = nb + ol;
            el = (idx < re) ? (int)es[idx] : n;
        }
        uint4 p[8];
#pragma unroll
        for (int b = 0; b < 8; ++b) {
            int s = __shfl(el_cur, obase + b);
            p[b] = *(const uint4*)(hw1u + (size_t)s * 32 + ol * 4);
        }
#pragma unroll
        for (int b = 0; b < 8; ++b) {
            acc2(c0, p[b].x); acc2(c1, p[b].y);
            acc2(c2, p[b].z); acc2(c3, p[b].w);
        }
    }
    if (valid) {
        float4 bb0 = ((const float4*)b1)[ol * 2];
        float4 bb1 = ((const float4*)b1)[ol * 2 + 1];
        float h0 = fmaxf(c0.x * di + bb0.x, 0.f);
        float h1 = fmaxf(c0.y * di + bb0.y, 0.f);
        float h2 = fmaxf(c1.x * di + bb0.z, 0.f);
        float h3 = fmaxf(c1.y * di + bb0.w, 0.f);
        float h4 = fmaxf(c2.x * di + bb1.x, 0.f);
        float h5 = fmaxf(c2.y * di + bb1.y, 0.f);
        float h6 = fmaxf(c3.x * di + bb1.z, 0.f);
        float h7 = fmaxf(c3.y * di + bb1.w, 0.f);
        // hb = dinv * h (source weight for layer-2 aggregation), bf16-packed
        uint4 st;
        st.x = (uint_t)f2bf(h0 * di) | ((uint_t)f2bf(h1 * di) << 16);
        st.y = (uint_t)f2bf(h2 * di) | ((uint_t)f2bf(h3 * di) << 16);
        st.z = (uint_t)f2bf(h4 * di) | ((uint_t)f2bf(h5 * di) << 16);
        st.w = (uint_t)f2bf(h6 * di) | ((uint_t)f2bf(h7 * di) << 16);
        *(uint4*)(hb + (size_t)node * HID + ol * 8) = st;
    }
}

// ---- agg2 + fused GEMM2: octet gather over hb rows, then same-wave LDS dot ----
// Same (256,4) + es-prefetch treatment as agg1; dot epilogue unchanged.
__global__ __launch_bounds__(256, 4) void k_agg2(
    const int* __restrict__ row_start, const uint_t* __restrict__ es,
    const float* __restrict__ dinv, const uint_t* __restrict__ hbu,
    const float* __restrict__ W2, const float* __restrict__ b2,
    float* __restrict__ out, int n)
{
    __shared__ float wsm[HID * NC];   // 10 KB, W2 row-major [64][40]
    __shared__ float hsm[32][68];     // 32 nodes x 64ch (+pad)
    for (int i = threadIdx.x; i < HID * NC; i += 256) wsm[i] = W2[i];
    __syncthreads();

    int lane = threadIdx.x & 63;
    int obase = lane & 56;
    int ol = lane & 7;
    int slot = threadIdx.x >> 3;        // node slot within block (0..31)
    int node = blockIdx.x * 32 + slot;
    bool valid = node < n;
    int rs = valid ? row_start[node] : 0;
    int re = valid ? row_start[node + 1] : 0;
    float di = valid ? dinv[node] : 0.f;
    int selfrow = valid ? node : n;

    f32x2 c0, c1, c2, c3;
    {
        uint4 sp = *(const uint4*)(hbu + (size_t)selfrow * 32 + ol * 4);
        c0 = (f32x2){0.f, 0.f}; c1 = c0; c2 = c0; c3 = c0;
        acc2(c0, sp.x); acc2(c1, sp.y); acc2(c2, sp.z); acc2(c3, sp.w);
    }
    int el = n;
    if (rs < re) {
        int idx = rs + ol;
        el = (idx < re) ? (int)es[idx] : n;   // pad -> zero sentinel
    }
    for (int base = rs; base < re; base += 8) {
        int el_cur = el;
        int nb = base + 8;
        if (nb < re) {                         // prefetch next window's indices
            int idx = nb + ol;
            el = (idx < re) ? (int)es[idx] : n;
        }
        uint4 p[8];
#pragma unroll
        for (int b = 0; b < 8; ++b) {
            int s = __shfl(el_cur, obase + b);
            p[b] = *(const uint4*)(hbu + (size_t)s * 32 + ol * 4);
        }
#pragma unroll
        for (int b = 0; b < 8; ++b) {
            acc2(c0, p[b].x); acc2(c1, p[b].y);
            acc2(c2, p[b].z); acc2(c3, p[b].w);
        }
    }
    // hagg row (f32) -> LDS; garbage for invalid nodes (never stored to out)
    {
        float4 g0, g1;
        g0.x = c0.x * di; g0.y = c0.y * di; g0.z = c1.x * di; g0.w = c1.y * di;
        g1.x = c2.x * di; g1.y = c2.y * di; g1.z = c3.x * di; g1.w = c3.y * di;
        *(float4*)&hsm[slot][ol * 8] = g0;
        *(float4*)&hsm[slot][ol * 8 + 4] = g1;
    }
    // fused GEMM2: two passes of 4-node quarter-wave dot over the wave's rows
    int w8 = (threadIdx.x >> 6) * 8;    // wave's first slot
    int qm = lane >> 4;                 // quarter 0..3
    int lq = lane & 15;
    int lw = (lq < 10) ? lq : 0;
    const float4* w4 = (const float4*)wsm;     // [64][10] float4
#pragma unroll
    for (int pass = 0; pass < 2; ++pass) {
        int slot2 = w8 + pass * 4 + qm;
        int node2 = blockIdx.x * 32 + slot2;
        float4 acc = ((const float4*)b2)[lw];  // b2 as accumulator init
#pragma unroll 4
        for (int k4 = 0; k4 < 16; ++k4) {
            float4 hk = *(const float4*)&hsm[slot2][k4 * 4];
            float4 w0 = w4[(k4 * 4 + 0) * 10 + lw];
            float4 w1 = w4[(k4 * 4 + 1) * 10 + lw];
            float4 w2 = w4[(k4 * 4 + 2) * 10 + lw];
            float4 w3 = w4[(k4 * 4 + 3) * 10 + lw];
            acc.x += hk.x * w0.x + hk.y * w1.x + hk.z * w2.x + hk.w * w3.x;
            acc.y += hk.x * w0.y + hk.y * w1.y + hk.z * w2.y + hk.w * w3.y;
            acc.z += hk.x * w0.z + hk.y * w1.z + hk.z * w2.z + hk.w * w3.z;
            acc.w += hk.x * w0.w + hk.y * w1.w + hk.z * w2.w + hk.w * w3.w;
        }
        if (node2 < n && lq < 10)
            *(float4*)(out + (size_t)node2 * NC + lq * 4) = acc;
    }
}

extern "C" void kernel_launch(void* const* d_in, const int* in_sizes, int n_in,
                              void* d_out, int out_size, void* d_ws, size_t ws_size,
                              hipStream_t stream) {
    const float* x  = (const float*)d_in[0];   // f32 [N,128]
    const int* edge = (const int*)d_in[1];     // int32 [2,E]
    const float* W1 = (const float*)d_in[2];   // f32 [128,64]
    const float* b1 = (const float*)d_in[3];   // f32 [64]
    const float* W2 = (const float*)d_in[4];   // f32 [64,40]
    const float* b2 = (const float*)d_in[5];   // f32 [40]
    float* out      = (float*)d_out;           // f32 [N,40]

    const int n = in_sizes[0] / IN_CH;   // 100000
    const int e = in_sizes[1] / 2;       // 1600000
    const int* srcs = edge;
    const int* dsts = edge + e;

    // workspace layout (all segments 16B-aligned)
    int*      gcur      = (int*)d_ws;                       // 196 cursors (256 reserved)
    int*      row_start = gcur + 256;                       // NPAD (needs n+1)
    float*    dinv      = (float*)(row_start + NPAD);       // NPAD
    uint_t*   tmp       = (uint_t*)(dinv + NPAD);           // NBUK*CAP packed 4B
    uint_t*   es        = tmp + (size_t)NBUK * CAP;         // NEDGES src-only 4B
    ushort_t* Wp        = (ushort_t*)(es + NEDGES);         // 8192 bf16
    ushort_t* hw1       = Wp + 8192;                        // (N+1)*64 bf16 (sentinel row n)
    ushort_t* hb        = hw1 + (size_t)(NNODES + 1) * HID; // (N+1)*64 bf16 (sentinel row n)

    hipMemsetAsync(gcur, 0, NBUK * sizeof(int), stream);    // count-only cursors
    k_bin0<<<NBIN + 1, 256, 0, stream>>>(srcs, dsts, gcur, tmp, e, W1, Wp, hb, n);
    k_sort<<<NBUK, 256, 0, stream>>>(tmp, gcur, row_start, dinv, es, n, e);
    k_gemm1<<<(n + 63) / 64, 256, 0, stream>>>(x, Wp, dinv, hw1, n);
    k_agg1<<<(n + 31) / 32, 256, 0, stream>>>(row_start, es, dinv, (const uint_t*)hw1, b1, hb, n);
    k_agg2<<<(n + 31) / 32, 256, 0, stream>>>(row_start, es, dinv, (const uint_t*)hb, W2, b2, out, n);
}